// Round 8
// baseline (433.784 us; speedup 1.0000x reference)
//
#include <hip/hip_runtime.h>

// LSTM, barrier-free per-wave MFMA formulation. Round 14: skewed 2-group
// pipeline. B=4096, T=512, I=10, H=32, O=1. Gates i,f,g,o.
//
// R13 counters: MfmaUtil 25% + VALU 50% = sum-behavior; window 1060 cyc/step.
// Root cause: in-order issue. 16 back-to-back MFMAs backpressure the issue
// stage ~310 cyc (19.4 cyc/MFMA per-SIMD throughput); the only nearby VALU
// (own gates' exp2) DEPENDS on those MFMAs -> nothing fills the gaps, MFMA
// and VALU phases serialize.
//
// R14: two groups of 2 batches (X = 0,1; Y = 2,3), dup-8 each (R9-verified
// mapping), skewed half a step:
//   iter s: frag_Y(s); MFMA_Y(s) || act_X(s) [consumes X results issued
//           last phase, fully drained]; write h_X(s);
//           frag_X(s+1) [reads h_X(s)]; MFMA_X(s+1) || act_Y(s); write h_Y(s)
// Each MFMA block sits next to the OTHER group's independent act VALU ->
// the scheduler can interleave into the issue gaps. DS aliasing (h writes
// feed the next frag reads) pins the phase order. MFMA 32/step (620 cyc
// pipe) becomes the overlapped floor instead of a serial term.
//
// Per group: 8 tiles x {merged-K MFMA + h_hi MFMA} (R9 K-packing:
// A1 = {x_hat k0..9 | h_lo k10..31}, A2 = h_hi). R13 act: shared-denominator
// gates, 5 exp2 + 3 rcp per cell; 1 cell/lane/group (qh selects, R9 map:
// batch Q>>1, hid L+16*(Q&1)). fp16 2-term h split, lo dropped ch 0..9
// (absmax 2e-3 verified R9-R13). Biases folded into exp2 args.
//
// Single h buffer [2 planes][4 batches][32] fp16 = 512 B: with the skew,
// each slot is read exactly once before its overwrite (wave-ordered DS,
// no barriers ever).
//
// Grid: 1024 blocks x 64 threads (1 wave/block = 1/SIMD), 4 batches/wave,
// launch_bounds(64,1).

#define T_SZ 512
#define I_SZ 10
#define H_SZ 32

typedef _Float16 half8  __attribute__((ext_vector_type(8)));
typedef __fp16   fp16x2 __attribute__((ext_vector_type(2)));
typedef float    f32x4  __attribute__((ext_vector_type(4)));
typedef int      i32x4  __attribute__((ext_vector_type(4)));

union FH { i32x4 i; half8 h; };
static __device__ __forceinline__ half8 fragv(i32x4 v) { FH u; u.i = v; return u.h; }
static __device__ __forceinline__ half8 frag4(int a, int b, int c, int d) {
    FH u; u.i = (i32x4){a, b, c, d}; return u.h;
}

// pack 2 fp32 -> 2 fp16 in one dword (v_cvt_pkrtz_f16_f32)
static __device__ __forceinline__ int pk16(float lo, float hi) {
    union { fp16x2 h; int i; } u;
    u.h = __builtin_amdgcn_cvt_pkrtz(lo, hi);
    return u.i;
}

#define MFMAH(A, B, C) __builtin_amdgcn_mfma_f32_16x16x32_f16((A), (B), (C), 0, 0, 0)
#define EXP2(x) __builtin_amdgcn_exp2f(x)
#define RCP(x)  __builtin_amdgcn_rcpf(x)

// 8 tiles x 2 MFMAs -> v[0..7] = C reg 0 of each tile
#define GEMM8(vout, mf, hhi)                                                         \
    do {                                                                             \
        _Pragma("unroll")                                                            \
        for (int tau = 0; tau < 8; ++tau) {                                          \
            f32x4 acc = MFMAH(mf, frag4(bm[tau][0], bm[tau][1], bm[tau][2],          \
                                        bm[tau][3]), zerov);                         \
            acc = MFMAH(hhi, frag4(bhh[tau][0], bhh[tau][1], bhh[tau][2],            \
                                   bhh[tau][3]), acc);                               \
            vout[tau] = acc[0];                                                      \
        }                                                                            \
    } while (0)

// R13 shared-denominator act for one cell (qh selects even/odd tiles)
#define ACT_CELL(v, cst, hout)                                                       \
    do {                                                                             \
        float vi = qh ? v[1] : v[0];                                                 \
        float vf = qh ? v[3] : v[2];                                                 \
        float vg = qh ? v[5] : v[4];                                                 \
        float vo = qh ? v[7] : v[6];                                                 \
        float eA = EXP2(fmaf(nL, vi, mbi));                                          \
        float eF = EXP2(fmaf(nL, vf, mbf));                                          \
        float eG = EXP2(fmaf(m2, vg, mbg));                                          \
        float eO = EXP2(fmaf(nL, vo, mbo));                                          \
        float fg  = RCP(1.0f + eF);                                                  \
        float igg = (1.0f - eG) * RCP((1.0f + eA) * (1.0f + eG));                    \
        cst = fmaf(fg, cst, igg);                                                    \
        float eD = EXP2(m2 * cst);                                                   \
        hout = (1.0f - eD) * RCP((1.0f + eO) * (1.0f + eD));                         \
    } while (0)

__global__ __launch_bounds__(64, 1)
void lstm_wave(const float* __restrict__ x, const float* __restrict__ W_ih,
               const float* __restrict__ W_hh, const float* __restrict__ b_ih,
               const float* __restrict__ b_hh, const float* __restrict__ W_dense,
               const float* __restrict__ b_dense, float* __restrict__ out)
{
    const int lane  = threadIdx.x;        // 0..63 (block = one wave)
    const int L     = lane & 15;          // A m-row / C col
    const int Q     = lane >> 4;          // k-quad
    const int bbase = blockIdx.x * 4;     // 1024 blocks x 4 batches

    const int bAg  = L >> 3;              // A-side batch within group (dup-8)
    const int bAct = Q >> 1;              // act-side batch within group
    const int hidA = L + 16 * (Q & 1);    // act-side hidden index

    // ---- B-fragments for all 8 tiles (one-time, shared by both groups) ----
    // tile tau = 2*gate + hhalf: W row = 32*gate + 16*hhalf + L
    int bhh[8][4];
    int bm[8][4];
    #pragma unroll
    for (int tau = 0; tau < 8; ++tau) {
        const int wr = 32 * (tau >> 1) + 16 * (tau & 1) + L;
        const float* ph = W_hh + wr * H_SZ + 8 * Q;
        #pragma unroll
        for (int d = 0; d < 4; ++d) {
            float2 v = *(const float2*)(ph + 2 * d);
            bhh[tau][d] = pk16(v.x, v.y);
        }
        if (Q == 0) {
            const float* pi = W_ih + wr * I_SZ;       // k0..7 = W_ih cols 0..7
            #pragma unroll
            for (int d = 0; d < 4; ++d) {
                float2 v = *(const float2*)(pi + 2 * d);
                bm[tau][d] = pk16(v.x, v.y);
            }
        } else if (Q == 1) {
            // k8,9 = W_ih cols 8,9; k10..15 = W_hh cols 10..15
            float2 v = *(const float2*)(W_ih + wr * I_SZ + 8);
            bm[tau][0] = pk16(v.x, v.y);
            #pragma unroll
            for (int d = 1; d < 4; ++d) {
                float2 w = *(const float2*)(W_hh + wr * H_SZ + 8 + 2 * d);
                bm[tau][d] = pk16(w.x, w.y);
            }
        } else {
            bm[tau][0] = bhh[tau][0]; bm[tau][1] = bhh[tau][1];
            bm[tau][2] = bhh[tau][2]; bm[tau][3] = bhh[tau][3];
        }
    }

    // ---- biases folded into exp2 args (hidA same for both groups) ----
    const float nL = -1.4426950f;     // -log2(e)       (sigmoid)
    const float m2 = -2.8853901f;     // -2*log2(e)     (tanh via (1-D)/(1+D))
    const float mbi = nL * (b_ih[hidA]      + b_hh[hidA]);
    const float mbf = nL * (b_ih[32 + hidA] + b_hh[32 + hidA]);
    const float mbg = m2 * (b_ih[64 + hidA] + b_hh[64 + hidA]);
    const float mbo = nL * (b_ih[96 + hidA] + b_hh[96 + hidA]);

    // ---- per-wave LDS h buffer: [plane hi/lo][batch 0..3][hid] fp16 ----
    // batches 0,1 = group X; 2,3 = group Y. Single buffer (skew-safe).
    __shared__ __attribute__((aligned(16))) _Float16 hbuf[2][4][H_SZ];  // 512 B
    {
        int* zz = (int*)&hbuf[0][0][0];
        zz[lane] = 0; zz[lane + 64] = 0;
    }
    // wave-ordered DS: zeros visible to this wave's later reads, no barrier.

    // ---- x streams: 2-deep per group ----
    const float* xrowX = x + (size_t)(bbase + bAg)     * (T_SZ * I_SZ);
    const float* xrowY = x + (size_t)(bbase + 2 + bAg) * (T_SZ * I_SZ);
    // Y: idx0 (yA) = step 0, idx1 (yB) = step 1 (phase A of step s uses idx s&1)
    float2 yA0 = *(const float2*)(xrowY + 0), yA1 = *(const float2*)(xrowY + 2),
           yA2 = *(const float2*)(xrowY + 4), yA3 = *(const float2*)(xrowY + 6),
           yA4 = *(const float2*)(xrowY + 8);
    float2 yB0 = *(const float2*)(xrowY + I_SZ + 0), yB1 = *(const float2*)(xrowY + I_SZ + 2),
           yB2 = *(const float2*)(xrowY + I_SZ + 4), yB3 = *(const float2*)(xrowY + I_SZ + 6),
           yB4 = *(const float2*)(xrowY + I_SZ + 8);
    // X: phase B of step s issues step s+1 -> idx (s+1)&1. Init: idx1 = step 1,
    // idx0 = step 2 (first idx0 use is s=1 -> step 2).
    float2 xB0 = *(const float2*)(xrowX + I_SZ + 0), xB1 = *(const float2*)(xrowX + I_SZ + 2),
           xB2 = *(const float2*)(xrowX + I_SZ + 4), xB3 = *(const float2*)(xrowX + I_SZ + 6),
           xB4 = *(const float2*)(xrowX + I_SZ + 8);
    float2 xA0 = *(const float2*)(xrowX + 2 * I_SZ + 0), xA1 = *(const float2*)(xrowX + 2 * I_SZ + 2),
           xA2 = *(const float2*)(xrowX + 2 * I_SZ + 4), xA3 = *(const float2*)(xrowX + 2 * I_SZ + 6),
           xA4 = *(const float2*)(xrowX + 2 * I_SZ + 8);

    const f32x4 zerov = {0.f, 0.f, 0.f, 0.f};
    float cstX = 0.0f, cstY = 0.0f;
    float hXlast = 0.0f, hYlast = 0.0f;
    const bool q0 = (Q == 0), q1 = (Q == 1);
    const bool qh = (Q & 1);

    // ---- prologue: issue MFMA_X(0) from zero h-state ----
    float vX[8];
    {
        float2 a0 = *(const float2*)(xrowX + 0), a1 = *(const float2*)(xrowX + 2),
               a2 = *(const float2*)(xrowX + 4), a3 = *(const float2*)(xrowX + 6),
               a4 = *(const float2*)(xrowX + 8);
        int p0 = pk16(a0.x, a0.y), p1 = pk16(a1.x, a1.y), p2 = pk16(a2.x, a2.y),
            p3 = pk16(a3.x, a3.y), p4 = pk16(a4.x, a4.y);
        half8 mf0 = fragv((i32x4){ q0 ? p0 : (q1 ? p4 : 0),
                                   q0 ? p1 : 0, q0 ? p2 : 0, q0 ? p3 : 0 });
        half8 hz = fragv((i32x4){0, 0, 0, 0});
        GEMM8(vX, mf0, hz);
    }

    for (int t = 0; t < T_SZ; t += 2) {
        #pragma unroll
        for (int u = 0; u < 2; ++u) {
            const int s = t + u;

            // ======== phase A: frag_Y(s) + MFMA_Y(s)  ||  act_X(s) ========
            float vY[8];
            {
                i32x4 hhiY_ = *(const i32x4*)&hbuf[0][2 + bAg][8 * Q];
                i32x4 loY_  = *(const i32x4*)&hbuf[1][2 + bAg][8 * Q];
                float2 w0 = u ? yB0 : yA0, w1 = u ? yB1 : yA1, w2 = u ? yB2 : yA2,
                       w3 = u ? yB3 : yA3, w4 = u ? yB4 : yA4;
                int p0 = pk16(w0.x, w0.y), p1 = pk16(w1.x, w1.y), p2 = pk16(w2.x, w2.y),
                    p3 = pk16(w3.x, w3.y), p4 = pk16(w4.x, w4.y);
                half8 mfY = fragv((i32x4){ q0 ? p0 : (q1 ? p4 : loY_[0]),
                                           q0 ? p1 : loY_[1],
                                           q0 ? p2 : loY_[2],
                                           q0 ? p3 : loY_[3] });
                half8 hhiY = fragv(hhiY_);
                GEMM8(vY, mfY, hhiY);
            }
            // act_X(s): independent of MFMA_Y -> interleaves into issue gaps
            {
                float hv;
                ACT_CELL(vX, cstX, hv);
                hXlast = hv;
                _Float16 hh = (_Float16)hv;
                _Float16 hl = (_Float16)(hv - (float)hh);
                hbuf[0][bAct][hidA] = hh;
                hbuf[1][bAct][hidA] = hl;
            }
            // refill Y set idx u <- x_Y(s+2)
            if (s + 2 < T_SZ) {
                const float* xr = xrowY + (s + 2) * I_SZ;
                if (u == 0) {
                    yA0 = *(const float2*)(xr + 0); yA1 = *(const float2*)(xr + 2);
                    yA2 = *(const float2*)(xr + 4); yA3 = *(const float2*)(xr + 6);
                    yA4 = *(const float2*)(xr + 8);
                } else {
                    yB0 = *(const float2*)(xr + 0); yB1 = *(const float2*)(xr + 2);
                    yB2 = *(const float2*)(xr + 4); yB3 = *(const float2*)(xr + 6);
                    yB4 = *(const float2*)(xr + 8);
                }
            }

            // ======== phase B: frag_X(s+1) + MFMA_X(s+1)  ||  act_Y(s) ========
            if (s + 1 < T_SZ) {
                i32x4 hhiX_ = *(const i32x4*)&hbuf[0][bAg][8 * Q];   // h_X(s), just written
                i32x4 loX_  = *(const i32x4*)&hbuf[1][bAg][8 * Q];
                float2 z0 = u ? xA0 : xB0, z1 = u ? xA1 : xB1, z2 = u ? xA2 : xB2,
                       z3 = u ? xA3 : xB3, z4 = u ? xA4 : xB4;   // idx (s+1)&1 = u^1
                int p0 = pk16(z0.x, z0.y), p1 = pk16(z1.x, z1.y), p2 = pk16(z2.x, z2.y),
                    p3 = pk16(z3.x, z3.y), p4 = pk16(z4.x, z4.y);
                half8 mfX = fragv((i32x4){ q0 ? p0 : (q1 ? p4 : loX_[0]),
                                           q0 ? p1 : loX_[1],
                                           q0 ? p2 : loX_[2],
                                           q0 ? p3 : loX_[3] });
                half8 hhiX = fragv(hhiX_);
                GEMM8(vX, mfX, hhiX);
                // refill X set idx u^1 <- x_X(s+3)
                if (s + 3 < T_SZ) {
                    const float* xr = xrowX + (s + 3) * I_SZ;
                    if (u == 0) {
                        xB0 = *(const float2*)(xr + 0); xB1 = *(const float2*)(xr + 2);
                        xB2 = *(const float2*)(xr + 4); xB3 = *(const float2*)(xr + 6);
                        xB4 = *(const float2*)(xr + 8);
                    } else {
                        xA0 = *(const float2*)(xr + 0); xA1 = *(const float2*)(xr + 2);
                        xA2 = *(const float2*)(xr + 4); xA3 = *(const float2*)(xr + 6);
                        xA4 = *(const float2*)(xr + 8);
                    }
                }
            }
            // act_Y(s): independent of MFMA_X(s+1) -> interleaves
            {
                float hv;
                ACT_CELL(vY, cstY, hv);
                hYlast = hv;
                _Float16 hh = (_Float16)hv;
                _Float16 hl = (_Float16)(hv - (float)hh);
                hbuf[0][2 + bAct][hidA] = hh;
                hbuf[1][2 + bAct][hidA] = hl;
            }
            // wave-ordered DS: next phase's reads see these writes.
        }
    }

    // ---- dense head: out[b] = h . W_dense + b_dense ----
    // per group: batch bAct=0 in lanes 0-31, bAct=1 in lanes 32-63
    float vx = hXlast * W_dense[hidA];
    float vy = hYlast * W_dense[hidA];
    #pragma unroll
    for (int m = 16; m >= 1; m >>= 1) {
        vx += __shfl_xor(vx, m);          // reduce within 32-lane halves
        vy += __shfl_xor(vy, m);
    }
    if (lane == 0)  { out[bbase + 0] = vx + b_dense[0]; out[bbase + 2] = vy + b_dense[0]; }
    if (lane == 32) { out[bbase + 1] = vx + b_dense[0]; out[bbase + 3] = vy + b_dense[0]; }
}

extern "C" void kernel_launch(void* const* d_in, const int* in_sizes, int n_in,
                              void* d_out, int out_size, void* d_ws, size_t ws_size,
                              hipStream_t stream) {
    const float* x       = (const float*)d_in[0];
    const float* W_ih    = (const float*)d_in[1];
    const float* W_hh    = (const float*)d_in[2];
    const float* b_ih    = (const float*)d_in[3];
    const float* b_hh    = (const float*)d_in[4];
    const float* W_dense = (const float*)d_in[5];
    const float* b_dense = (const float*)d_in[6];
    float* out = (float*)d_out;

    // 1024 blocks x 64 threads = 1024 independent waves (1/SIMD), 4 batches
    // each (2 skew-pipelined groups of 2)
    lstm_wave<<<dim3(1024), dim3(64), 0, stream>>>(
        x, W_ih, W_hh, b_ih, b_hh, W_dense, b_dense, out);
}

// Round 9
// 332.913 us; speedup vs baseline: 1.3030x; 1.3030x over previous
//
#include <hip/hip_runtime.h>

// LSTM, barrier-free per-wave MFMA formulation. Round 15: R13 skeleton with
// the LDS h-ring replaced by an in-register transpose (shfl_xor + pk16 +
// ds_bpermute). B=4096, T=512, I=10, H=32, O=1. Gates i,f,g,o.
//
// R14 post-mortem: skewed 2-group again doubled MFMA/batch (dup-8) -> 364us.
// Confirmed rule (R11+R14): never double MFMAs/batch for overlap. R13 stays.
//
// R13 budget: window 1070 cyc/step = MFMA 265 + VALU 530 (256 = 16 trans,
// irreducible) + ~275 serial tail. Tail = last MFMA drain + exp2 + combines
// + pack + LDS h write->read (~130-150, two LDS traversals on the critical
// path). R15 removes the LDS ring:
//   producer: t0 = shfl_xor(hv0,1); t1 = shfl_xor(hv1,1);
//     comb = evenL ? pk16(hv0,t0) : pk16(t1,hv1)
//     -> lane (Q,L) carries ch-pair (L,L+1) [even] / (L+15,L+16) [odd] of
//        batch Q; all 16 pairs/batch in ONE reg (hi and lo planes).
//   consumer: A-frag dword d = ds_bpermute(comb, idx[d]) with loop-invariant
//     idx = 4*(16*(L>>2) + (Q<2 ? 8Q+2d : 8Q+2d-15)).
// Ring latency ~130-150 -> ~70-80; LDS usage -> 0. Numerics bit-identical
// to R13 (same fp16 2-term split, same dropped lo ch0..9; absmax 2e-3).
//
// Mappings (verified R3-R13): A row m = L (batch L>>2, dup-4), A[m][k=8Q+j];
// C col=L, row=4Q+reg, reg0 of quad Q = batch Q. Act: lane (Q,L) owns batch
// Q, hids {L, L+16}; cell0 = even tiles, cell1 = odd. Merged-K (R9): per
// tile MFMA1 A={x_hat k0..9 | h_lo k10..31}, MFMA2 A=h_hi. Shared-denominator
// act (R13): 5 exp2 + 3 rcp per cell. Gate-interleaved schedule (R13).
//
// Grid: 1024 blocks x 64 threads (1 wave/block = 1/SIMD), 4 batches/wave,
// launch_bounds(64,1). No LDS, no barriers.

#define T_SZ 512
#define I_SZ 10
#define H_SZ 32

typedef _Float16 half8  __attribute__((ext_vector_type(8)));
typedef __fp16   fp16x2 __attribute__((ext_vector_type(2)));
typedef float    f32x4  __attribute__((ext_vector_type(4)));
typedef int      i32x4  __attribute__((ext_vector_type(4)));

union FH { i32x4 i; half8 h; };
static __device__ __forceinline__ half8 fragv(i32x4 v) { FH u; u.i = v; return u.h; }
static __device__ __forceinline__ half8 frag4(int a, int b, int c, int d) {
    FH u; u.i = (i32x4){a, b, c, d}; return u.h;
}

// pack 2 fp32 -> 2 fp16 in one dword (v_cvt_pkrtz_f16_f32)
static __device__ __forceinline__ int pk16(float lo, float hi) {
    union { fp16x2 h; int i; } u;
    u.h = __builtin_amdgcn_cvt_pkrtz(lo, hi);
    return u.i;
}

#define MFMAH(A, B, C) __builtin_amdgcn_mfma_f32_16x16x32_f16((A), (B), (C), 0, 0, 0)
#define EXP2(x) __builtin_amdgcn_exp2f(x)
#define RCP(x)  __builtin_amdgcn_rcpf(x)
#define BPERM(i, s) __builtin_amdgcn_ds_bpermute((i), (s))

__global__ __launch_bounds__(64, 1)
void lstm_wave(const float* __restrict__ x, const float* __restrict__ W_ih,
               const float* __restrict__ W_hh, const float* __restrict__ b_ih,
               const float* __restrict__ b_hh, const float* __restrict__ W_dense,
               const float* __restrict__ b_dense, float* __restrict__ out)
{
    const int lane  = threadIdx.x;        // 0..63 (block = one wave)
    const int L     = lane & 15;          // A m-row / C col
    const int Q     = lane >> 4;          // k-quad / C row-quad (= act batch)
    const int bbase = blockIdx.x * 4;     // 1024 blocks x 4 batches

    const int bA = L >> 2;                // A-side batch (4 dup rows per batch)
    const int h0 = L, h1 = L + 16;        // this lane's two hidden channels

    // ---- bpermute indices (loop-invariant): frag dword d <- comb[src] ----
    // src lane = 16*(L>>2) + srcL; srcL = (Q<2) ? (8Q+2d) : (8Q+2d-15)
    int idx0, idx1, idx2, idx3;
    {
        const int base = 16 * bA;
        const int off  = (Q < 2) ? (8 * Q) : (8 * Q - 15);
        idx0 = 4 * (base + off + 0);
        idx1 = 4 * (base + off + 2);
        idx2 = 4 * (base + off + 4);
        idx3 = 4 * (base + off + 6);
    }
    const bool evenL = ((L & 1) == 0);

    // ---- B-fragments for all 8 tiles (one-time) ----
    // tile tau = 2*gate + hhalf: W row = 32*gate + 16*hhalf + L
    int bhh[8][4];
    int bm[8][4];
    #pragma unroll
    for (int tau = 0; tau < 8; ++tau) {
        const int wr = 32 * (tau >> 1) + 16 * (tau & 1) + L;
        const float* ph = W_hh + wr * H_SZ + 8 * Q;
        #pragma unroll
        for (int d = 0; d < 4; ++d) {
            float2 v = *(const float2*)(ph + 2 * d);
            bhh[tau][d] = pk16(v.x, v.y);
        }
        if (Q == 0) {
            const float* pi = W_ih + wr * I_SZ;       // k0..7 = W_ih cols 0..7
            #pragma unroll
            for (int d = 0; d < 4; ++d) {
                float2 v = *(const float2*)(pi + 2 * d);
                bm[tau][d] = pk16(v.x, v.y);
            }
        } else if (Q == 1) {
            // k8,9 = W_ih cols 8,9; k10..15 = W_hh cols 10..15
            float2 v = *(const float2*)(W_ih + wr * I_SZ + 8);
            bm[tau][0] = pk16(v.x, v.y);
            #pragma unroll
            for (int d = 1; d < 4; ++d) {
                float2 w = *(const float2*)(W_hh + wr * H_SZ + 8 + 2 * d);
                bm[tau][d] = pk16(w.x, w.y);
            }
        } else {
            bm[tau][0] = bhh[tau][0]; bm[tau][1] = bhh[tau][1];
            bm[tau][2] = bhh[tau][2]; bm[tau][3] = bhh[tau][3];
        }
    }

    // ---- biases folded into exp2 args; per gate, both cells ----
    const float nL = -1.4426950f;     // -log2(e)       (sigmoid)
    const float m2 = -2.8853901f;     // -2*log2(e)     (tanh via (1-D)/(1+D))
    float mb0[4], mb1[4];             // gate order i,f,g,o
    #pragma unroll
    for (int gt = 0; gt < 4; ++gt) {
        const float sc = (gt == 2) ? m2 : nL;
        mb0[gt] = sc * (b_ih[32 * gt + h0] + b_hh[32 * gt + h0]);
        mb1[gt] = sc * (b_ih[32 * gt + h1] + b_hh[32 * gt + h1]);
    }

    // ---- x stream: 2-deep prefetch (each lane loads its A-side batch row) ----
    const float* xrow = x + (size_t)(bbase + bA) * (T_SZ * I_SZ);
    float2 xa0 = *(const float2*)(xrow + 0), xa1 = *(const float2*)(xrow + 2),
           xa2 = *(const float2*)(xrow + 4), xa3 = *(const float2*)(xrow + 6),
           xa4 = *(const float2*)(xrow + 8);
    float2 xb0 = *(const float2*)(xrow + I_SZ + 0), xb1 = *(const float2*)(xrow + I_SZ + 2),
           xb2 = *(const float2*)(xrow + I_SZ + 4), xb3 = *(const float2*)(xrow + I_SZ + 6),
           xb4 = *(const float2*)(xrow + I_SZ + 8);

    const f32x4 zerov = {0.f, 0.f, 0.f, 0.f};
    float cst0 = 0.0f, cst1 = 0.0f;
    float h0last = 0.0f, h1last = 0.0f;
    int comb_hi = 0, comb_lo = 0;         // h(0) = 0
    const bool q0 = (Q == 0), q1 = (Q == 1);

    for (int t = 0; t < T_SZ; t += 2) {
        #pragma unroll
        for (int u = 0; u < 2; ++u) {
            // ---- consumer: h fragments via bpermute (replaces LDS reads) ----
            int hd0 = BPERM(idx0, comb_hi), hd1 = BPERM(idx1, comb_hi),
                hd2 = BPERM(idx2, comb_hi), hd3 = BPERM(idx3, comb_hi);
            int ld0 = BPERM(idx0, comb_lo), ld1 = BPERM(idx1, comb_lo),
                ld2 = BPERM(idx2, comb_lo), ld3 = BPERM(idx3, comb_lo);

            // x_hat packs (u is compile-time; selects fold away)
            float2 y0 = u ? xb0 : xa0, y1 = u ? xb1 : xa1, y2 = u ? xb2 : xa2,
                   y3 = u ? xb3 : xa3, y4 = u ? xb4 : xa4;
            int p0 = pk16(y0.x, y0.y), p1 = pk16(y1.x, y1.y), p2 = pk16(y2.x, y2.y),
                p3 = pk16(y3.x, y3.y), p4 = pk16(y4.x, y4.y);

            // merged A-frag: k0..9 = x_hat, k10..31 = h_lo channels 10..31
            half8 mf = fragv((i32x4){ q0 ? p0 : (q1 ? p4 : ld0),
                                      q0 ? p1 : ld1,
                                      q0 ? p2 : ld2,
                                      q0 ? p3 : ld3 });
            half8 hhi = fragv((i32x4){hd0, hd1, hd2, hd3});

            // ---- gate loop: MFMA tile-pair, then that gate's exp2 pair ----
            float e0[4], e1[4];
            #pragma unroll
            for (int gt = 0; gt < 4; ++gt) {
                const float sc = (gt == 2) ? m2 : nL;
                const int te = 2 * gt, to = 2 * gt + 1;
                f32x4 ae = MFMAH(mf,  frag4(bm[te][0],  bm[te][1],  bm[te][2],  bm[te][3]),  zerov);
                ae       = MFMAH(hhi, frag4(bhh[te][0], bhh[te][1], bhh[te][2], bhh[te][3]), ae);
                f32x4 ao = MFMAH(mf,  frag4(bm[to][0],  bm[to][1],  bm[to][2],  bm[to][3]),  zerov);
                ao       = MFMAH(hhi, frag4(bhh[to][0], bhh[to][1], bhh[to][2], bhh[to][3]), ao);
                e0[gt] = EXP2(fmaf(sc, ae[0], mb0[gt]));
                e1[gt] = EXP2(fmaf(sc, ao[0], mb1[gt]));
            }

            // refill consumed x set from t+2+u (loads fly under the combines)
            if (t + 2 + u < T_SZ) {
                const float* xr = xrow + (t + 2 + u) * I_SZ;
                if (u == 0) {
                    xa0 = *(const float2*)(xr + 0); xa1 = *(const float2*)(xr + 2);
                    xa2 = *(const float2*)(xr + 4); xa3 = *(const float2*)(xr + 6);
                    xa4 = *(const float2*)(xr + 8);
                } else {
                    xb0 = *(const float2*)(xr + 0); xb1 = *(const float2*)(xr + 2);
                    xb2 = *(const float2*)(xr + 4); xb3 = *(const float2*)(xr + 6);
                    xb4 = *(const float2*)(xr + 8);
                }
            }

            // ---- combine chains (shared-denominator gates, 3 rcp/cell) ----
            // i*g~ = (1-B)/((1+A)(1+B)); f = 1/(1+F); h = (1-D)/((1+O)(1+D))
            float hv0, hv1;
            {
                float eA = e0[0], eF = e0[1], eG = e0[2], eO = e0[3];
                float fg  = RCP(1.0f + eF);
                float igg = (1.0f - eG) * RCP((1.0f + eA) * (1.0f + eG));
                cst0 = fmaf(fg, cst0, igg);
                float eD = EXP2(m2 * cst0);
                hv0 = (1.0f - eD) * RCP((1.0f + eO) * (1.0f + eD));
            }
            {
                float eA = e1[0], eF = e1[1], eG = e1[2], eO = e1[3];
                float fg  = RCP(1.0f + eF);
                float igg = (1.0f - eG) * RCP((1.0f + eA) * (1.0f + eG));
                cst1 = fmaf(fg, cst1, igg);
                float eD = EXP2(m2 * cst1);
                hv1 = (1.0f - eD) * RCP((1.0f + eO) * (1.0f + eD));
            }
            h0last = hv0;
            h1last = hv1;

            // ---- producer: build comb regs for next step (replaces LDS writes)
            // hi/lo split identical to R13's LDS path (bit-identical numerics)
            {
                float t0 = __shfl_xor(hv0, 1);   // partner's cell0 h
                float t1 = __shfl_xor(hv1, 1);   // partner's cell1 h
                // own lo terms
                float o0h = (float)(_Float16)hv0;
                float o1h = (float)(_Float16)hv1;
                float lo0 = hv0 - o0h;
                float lo1 = hv1 - o1h;
                // partner lo terms (recomputed locally; no extra shfl)
                float p0h = (float)(_Float16)t0;
                float p1h = (float)(_Float16)t1;
                float pl0 = t0 - p0h;
                float pl1 = t1 - p1h;
                // even lane: ch-pair (L, L+1); odd lane: ch-pair (L+15, L+16)
                comb_hi = evenL ? pk16(hv0, t0) : pk16(t1, hv1);
                comb_lo = evenL ? pk16(lo0, pl0) : pk16(pl1, lo1);
            }
        }
    }

    // ---- dense head: out[b] = h . W_dense + b_dense ----
    // lane (Q,L) holds hids {L, L+16} of batch Q; reduce over the 16-lane quad
    float v = h0last * W_dense[h0] + h1last * W_dense[h1];
    #pragma unroll
    for (int m = 8; m >= 1; m >>= 1)
        v += __shfl_xor(v, m);            // reduce within each 16-lane quad
    if (L == 0) out[bbase + Q] = v + b_dense[0];
}

extern "C" void kernel_launch(void* const* d_in, const int* in_sizes, int n_in,
                              void* d_out, int out_size, void* d_ws, size_t ws_size,
                              hipStream_t stream) {
    const float* x       = (const float*)d_in[0];
    const float* W_ih    = (const float*)d_in[1];
    const float* W_hh    = (const float*)d_in[2];
    const float* b_ih    = (const float*)d_in[3];
    const float* b_hh    = (const float*)d_in[4];
    const float* W_dense = (const float*)d_in[5];
    const float* b_dense = (const float*)d_in[6];
    float* out = (float*)d_out;

    // 1024 blocks x 64 threads = 1024 independent waves (1/SIMD), 4 batches each
    lstm_wave<<<dim3(1024), dim3(64), 0, stream>>>(
        x, W_ih, W_hh, b_ih, b_hh, W_dense, b_dense, out);
}